// Round 8
// baseline (185.735 us; speedup 1.0000x reference)
//
#include <hip/hip_runtime.h>
#include <hip/hip_bf16.h>

#define N_NODES 50000
#define N_EDGES 800000
#define D 128
#define NEG_SLOPE 0.2f
#define APAD 136                             // LDS row pitch (ushort): 2-way-only bank aliasing

#define FB 196                               // fine buckets: src >> 8 (256 nodes each)
#define BCAP 8192                            // per-bucket region capacity (avg fill ~4096)
#define CHUNK 4096
#define BIN_NBLK ((N_EDGES + CHUNK - 1) / CHUNK)   // 196
#define GROWS 64
#define GGRID ((N_NODES + GROWS - 1) / GROWS)      // 782

typedef __attribute__((ext_vector_type(8))) short bf16x8;
typedef __attribute__((ext_vector_type(4))) float f32x4;

__device__ inline unsigned short f2bf(float f) {
    union { float f; unsigned u; } v; v.f = f;
    const unsigned r = v.u + 0x7FFF + ((v.u >> 16) & 1);   // round-nearest-even
    return (unsigned short)(r >> 16);
}
__device__ inline unsigned fbits(float f) { union { float f; unsigned u; } v; v.f = f; return v.u; }
__device__ inline float ffrom(unsigned u) { union { unsigned u; float f; } v; v.u = u; return v.f; }

__device__ inline void unpack8(const float4 raw, float* o) {
    const unsigned w0 = fbits(raw.x), w1 = fbits(raw.y), w2 = fbits(raw.z), w3 = fbits(raw.w);
    o[0] = ffrom(w0 << 16); o[1] = ffrom(w0 & 0xffff0000u);
    o[2] = ffrom(w1 << 16); o[3] = ffrom(w1 & 0xffff0000u);
    o[4] = ffrom(w2 << 16); o[5] = ffrom(w2 & 0xffff0000u);
    o[6] = ffrom(w3 << 16); o[7] = ffrom(w3 & 0xffff0000u);
}

__device__ inline int scan256_incl(int* arr, int t, int v) {
    arr[t] = v; __syncthreads();
#pragma unroll
    for (int off = 1; off < 256; off <<= 1) {
        const int u = (t >= off) ? arr[t - off] : 0;
        __syncthreads();
        arr[t] += u;
        __syncthreads();
    }
    return arr[t];
}

// stage a 128x128 bf16 matrix (transposed layout [n][k]) into LDS [n][APAD]
__device__ __forceinline__ void stage_B_lds(unsigned short* Bs, const ushort* __restrict__ BT) {
    const int tid = threadIdx.x;
#pragma unroll
    for (int i = 0; i < 8; ++i) {
        const int idx = tid + i * 256;
        const int row = idx >> 4;
        const int c8 = (idx & 15) << 3;
        const float4 v = ((const float4*)BT)[idx];
        *(float4*)&Bs[row * APAD + c8] = v;
    }
}

// MFMA: C[rb..rb+63][0..127] = As(LDS) @ Bs(LDS, transposed), fp32 acc
template <bool OUT_F32>
__device__ __forceinline__ void mfma_from_lds(const unsigned short* Bs,
                                              const unsigned short* As,
                                              int rb, float* __restrict__ Cf,
                                              ushort* __restrict__ Cb, int nrows) {
    const int tid = threadIdx.x;
    const int w = tid >> 6, lane = tid & 63, m = lane & 15, kq = lane >> 4;
    f32x4 acc[8] = {};
    const unsigned short* Arow = &As[(w * 16 + m) * APAD + kq * 8];
#pragma unroll
    for (int kc = 0; kc < 4; ++kc) {
        const bf16x8 af = *(const bf16x8*)(Arow + kc * 32);
#pragma unroll
        for (int t2 = 0; t2 < 8; ++t2) {
            const bf16x8 bf = *(const bf16x8*)&Bs[(t2 * 16 + m) * APAD + kc * 32 + kq * 8];
            acc[t2] = __builtin_amdgcn_mfma_f32_16x16x32_bf16(af, bf, acc[t2], 0, 0, 0);
        }
    }
    const int orow0 = rb + w * 16 + kq * 4;   // C/D: col=lane&15, row=(lane>>4)*4+reg [m89]
#pragma unroll
    for (int t2 = 0; t2 < 8; ++t2) {
#pragma unroll
        for (int r = 0; r < 4; ++r) {
            const int row = orow0 + r;
            if (row < nrows) {
                const size_t o = (size_t)row * D + t2 * 16 + m;
                if (OUT_F32) Cf[o] = acc[t2][r];
                else         Cb[o] = f2bf(acc[t2][r]);
            }
        }
    }
}

// ---- kernel 1: chunk-staged binning (blocks 0..BIN_NBLK-1) + weight prep (tail) ----
__global__ __launch_bounds__(256) void bin_prep_kernel(const int* __restrict__ src,
                                                       const int* __restrict__ dst,
                                                       int* __restrict__ bucket_fill,
                                                       int2* __restrict__ binned,
                                                       const float* __restrict__ W_l,
                                                       const float* __restrict__ W_r,
                                                       const float* __restrict__ W,
                                                       ushort* __restrict__ MbT,
                                                       ushort* __restrict__ WbT) {
    if (blockIdx.x < BIN_NBLK) {
        __shared__ int hist[256];
        __shared__ int bstart[256];
        __shared__ int reserveS[256];
        __shared__ int fillL[256];
        __shared__ int2 pairs[CHUNK];
        __shared__ int targ[CHUNK];
        const int t = threadIdx.x;
        const int e0 = blockIdx.x * CHUNK;

        hist[t] = 0;
        __syncthreads();

        int s[16], d[16], b[16];
#pragma unroll
        for (int i = 0; i < 16; ++i) {
            const int e = e0 + i * 256 + t;
            if (e < N_EDGES) {
                s[i] = src[e]; d[i] = dst[e]; b[i] = s[i] >> 8;
                atomicAdd(&hist[b[i]], 1);
            } else b[i] = -1;
        }
        __syncthreads();
        const int hv = hist[t];
        const int incl = scan256_incl(bstart, t, hv);
        const int mystart = incl - hv;
        reserveS[t] = hv ? atomicAdd(&bucket_fill[t], hv) : 0;
        __syncthreads();
        bstart[t] = mystart;
        fillL[t] = mystart;
        __syncthreads();
#pragma unroll
        for (int i = 0; i < 16; ++i) {
            if (b[i] >= 0) {
                const int p = atomicAdd(&fillL[b[i]], 1);
                pairs[p] = make_int2(s[i], d[i]);
                const int pos = reserveS[b[i]] + (p - bstart[b[i]]);
                targ[p] = (pos < BCAP) ? (b[i] * BCAP + pos) : -1;   // overflow guard
            }
        }
        __syncthreads();
        const int nval = min(CHUNK, N_EDGES - e0);
        for (int j = t; j < nval; j += 256)
            if (targ[j] >= 0) binned[targ[j]] = pairs[j];
    } else {
        // MbT[n][k] = (W_l @ W_r^T)[k][n]; WbT[n][k] = W[k][n]
        const int a = (blockIdx.x - BIN_NBLK) * 2 + (threadIdx.x >> 7);  // k
        const int b2 = threadIdx.x & 127;                                // n
        float acc = 0.f;
#pragma unroll
        for (int c = 0; c < D; c += 4) {
            const float4 wl = *(const float4*)(W_l + a * D + c);
            const float4 wr = *(const float4*)(W_r + b2 * D + c);
            acc += wl.x * wr.x + wl.y * wr.y + wl.z * wr.z + wl.w * wr.w;
        }
        MbT[b2 * D + a] = f2bf(acc);
        WbT[b2 * D + a] = f2bf(W[a * D + b2]);
    }
}

// ---- kernel 2: convert 64 X-rows fp32->bf16 (global + LDS) then hM = Xb@M ----
__global__ __launch_bounds__(256) void convert_gemm1_kernel(const float4* __restrict__ Xf4,
                                                            ushort* __restrict__ Xb,
                                                            const ushort* __restrict__ MbT,
                                                            ushort* __restrict__ hMb) {
    __shared__ __align__(16) unsigned short Bs[D * APAD];
    __shared__ __align__(16) unsigned short As[GROWS * APAD];
    const int t = threadIdx.x;
    const int rb = blockIdx.x * GROWS;

    stage_B_lds(Bs, MbT);

#pragma unroll
    for (int i = 0; i < 4; ++i) {
        const int f2 = t + i * 256;          // 16B-group index, [0,1024)
        const int row = f2 >> 4;             // 0..63
        const int c8 = (f2 & 15) << 3;       // ushort col, multiple of 8
        ushort4 lo = {0, 0, 0, 0}, hi = {0, 0, 0, 0};
        if (rb + row < N_NODES) {
            const float4 a = Xf4[(size_t)(rb + row) * 32 + (c8 >> 2)];
            const float4 b = Xf4[(size_t)(rb + row) * 32 + (c8 >> 2) + 1];
            lo.x = f2bf(a.x); lo.y = f2bf(a.y); lo.z = f2bf(a.z); lo.w = f2bf(a.w);
            hi.x = f2bf(b.x); hi.y = f2bf(b.y); hi.z = f2bf(b.z); hi.w = f2bf(b.w);
            ushort* gp = Xb + (size_t)(rb + row) * D + c8;
            *(ushort4*)gp = lo;
            *(ushort4*)(gp + 4) = hi;
        }
        *(ushort4*)&As[row * APAD + c8] = lo;
        *(ushort4*)&As[row * APAD + c8 + 4] = hi;
    }
    __syncthreads();
    mfma_from_lds<false>(Bs, As, rb, nullptr, hMb, N_NODES);
}

// ---- kernel 3: fine scatter, one block per bucket; builds offsets + sorted_dst ----
__global__ __launch_bounds__(256) void fine_kernel(const int2* __restrict__ binned,
                                                   const int* __restrict__ bucket_fill,
                                                   int* __restrict__ offsets,
                                                   int* __restrict__ sorted_dst) {
    __shared__ int cntS[256];
    __shared__ int nh[256];
    __shared__ int ex[256];
    __shared__ int fill[256];
    __shared__ int dstbuf[BCAP];
    const int b = blockIdx.x;
    const int t = threadIdx.x;

    const int myc = (t < FB) ? bucket_fill[t] : 0;
    scan256_incl(cntS, t, myc);                       // inclusive bucket sums
    const int base = (b == 0) ? 0 : cntS[b - 1];
    int cnt = cntS[b] - base;
    if (cnt > BCAP) cnt = BCAP;

    nh[t] = 0;
    __syncthreads();
    const int2* bb = binned + (size_t)b * BCAP;
    for (int e = t; e < cnt; e += 256) atomicAdd(&nh[bb[e].x & 255], 1);
    __syncthreads();
    const int v = nh[t];
    const int incl2 = scan256_incl(ex, t, v);
    const int mystart = incl2 - v;
    const int node = b * 256 + t;
    if (node < N_NODES) offsets[node] = base + mystart;   // exclusive CSR starts
    fill[t] = mystart;
    __syncthreads();
    for (int e = t; e < cnt; e += 256) {
        const int2 sd = bb[e];
        const int p = atomicAdd(&fill[sd.x & 255], 1);
        dstbuf[p] = sd.y;
    }
    __syncthreads();
    for (int j = t; j < cnt; j += 256)
        sorted_dst[base + j] = dstbuf[j];
}

// ---- kernel 4: fused SDDMM + SpMM + gemm2. Block = 64 nodes; quarter-wave owns
// 4 nodes' edge lists; aggX rows stay in LDS; MFMA tail -> agg fp32 directly. ----
__global__ __launch_bounds__(256) void spmm_gemm2_kernel(const ushort* __restrict__ hMb,
                                                         const ushort* __restrict__ Xb,
                                                         const int* __restrict__ offsets,
                                                         const int* __restrict__ sorted_dst,
                                                         const ushort* __restrict__ WbT,
                                                         float* __restrict__ agg) {
    __shared__ __align__(16) unsigned short Bs[D * APAD];
    __shared__ __align__(16) unsigned short aggl[GROWS * APAD];
    const int t = threadIdx.x;
    const int rb = blockIdx.x * GROWS;
    const int lane = t & 63, w = t >> 6;
    const int q = lane >> 4, ql = lane & 15;
    const int qid = w * 4 + q;                   // 0..15, owns 4 nodes

    stage_B_lds(Bs, WbT);                        // hidden under the gather phase

    for (int i = 0; i < 4; ++i) {
        const int node = rb + qid * 4 + i;
        float acc[8] = {0.f, 0.f, 0.f, 0.f, 0.f, 0.f, 0.f, 0.f};
        if (node < N_NODES) {
            float hm[8];
            unpack8(*(const float4*)(hMb + (size_t)node * D + ql * 8), hm);
            const int start = offsets[node];
            const int end = (node == N_NODES - 1) ? N_EDGES : offsets[node + 1];
            int idx = start;
            while (idx + 3 < end) {              // 4 gathers in flight per quarter
                const int d0 = sorted_dst[idx];
                const int d1 = sorted_dst[idx + 1];
                const int d2 = sorted_dst[idx + 2];
                const int d3 = sorted_dst[idx + 3];
                const float4 r0 = *(const float4*)(Xb + (size_t)d0 * D + ql * 8);
                const float4 r1 = *(const float4*)(Xb + (size_t)d1 * D + ql * 8);
                const float4 r2 = *(const float4*)(Xb + (size_t)d2 * D + ql * 8);
                const float4 r3 = *(const float4*)(Xb + (size_t)d3 * D + ql * 8);
                float t0 = 0.f, t1 = 0.f, t2 = 0.f, t3 = 0.f;
                {
                    float x[8];
                    unpack8(r0, x);
#pragma unroll
                    for (int j = 0; j < 8; ++j) t0 = fmaf(hm[j], x[j], t0);
                    unpack8(r1, x);
#pragma unroll
                    for (int j = 0; j < 8; ++j) t1 = fmaf(hm[j], x[j], t1);
                    unpack8(r2, x);
#pragma unroll
                    for (int j = 0; j < 8; ++j) t2 = fmaf(hm[j], x[j], t2);
                    unpack8(r3, x);
#pragma unroll
                    for (int j = 0; j < 8; ++j) t3 = fmaf(hm[j], x[j], t3);
                }
#pragma unroll
                for (int mm = 1; mm < 16; mm <<= 1) {
                    t0 += __shfl_xor(t0, mm);
                    t1 += __shfl_xor(t1, mm);
                    t2 += __shfl_xor(t2, mm);
                    t3 += __shfl_xor(t3, mm);
                }
                const float e0 = t0 > 0.f ? t0 : NEG_SLOPE * t0;
                const float e1 = t1 > 0.f ? t1 : NEG_SLOPE * t1;
                const float e2 = t2 > 0.f ? t2 : NEG_SLOPE * t2;
                const float e3 = t3 > 0.f ? t3 : NEG_SLOPE * t3;
                {
                    float x[8];
                    unpack8(r0, x);
#pragma unroll
                    for (int j = 0; j < 8; ++j) acc[j] = fmaf(e0, x[j], acc[j]);
                    unpack8(r1, x);
#pragma unroll
                    for (int j = 0; j < 8; ++j) acc[j] = fmaf(e1, x[j], acc[j]);
                    unpack8(r2, x);
#pragma unroll
                    for (int j = 0; j < 8; ++j) acc[j] = fmaf(e2, x[j], acc[j]);
                    unpack8(r3, x);
#pragma unroll
                    for (int j = 0; j < 8; ++j) acc[j] = fmaf(e3, x[j], acc[j]);
                }
                idx += 4;
            }
            while (idx < end) {
                const int d0 = sorted_dst[idx];
                const float4 r0 = *(const float4*)(Xb + (size_t)d0 * D + ql * 8);
                float x[8];
                unpack8(r0, x);
                float t0 = 0.f;
#pragma unroll
                for (int j = 0; j < 8; ++j) t0 = fmaf(hm[j], x[j], t0);
#pragma unroll
                for (int mm = 1; mm < 16; mm <<= 1) t0 += __shfl_xor(t0, mm);
                const float e0 = t0 > 0.f ? t0 : NEG_SLOPE * t0;
#pragma unroll
                for (int j = 0; j < 8; ++j) acc[j] = fmaf(e0, x[j], acc[j]);
                ++idx;
            }
        }
        ushort4 o0, o1;
        o0.x = f2bf(acc[0]); o0.y = f2bf(acc[1]); o0.z = f2bf(acc[2]); o0.w = f2bf(acc[3]);
        o1.x = f2bf(acc[4]); o1.y = f2bf(acc[5]); o1.z = f2bf(acc[6]); o1.w = f2bf(acc[7]);
        unsigned short* lp = &aggl[(qid * 4 + i) * APAD + ql * 8];
        *(ushort4*)lp = o0;
        *(ushort4*)(lp + 4) = o1;
    }
    __syncthreads();
    mfma_from_lds<true>(Bs, aggl, rb, agg, nullptr, N_NODES);
}

extern "C" void kernel_launch(void* const* d_in, const int* in_sizes, int n_in,
                              void* d_out, int out_size, void* d_ws, size_t ws_size,
                              hipStream_t stream) {
    const float* X   = (const float*)d_in[0];
    const float* W   = (const float*)d_in[1];
    const float* W_r = (const float*)d_in[2];
    const float* W_l = (const float*)d_in[3];
    const int* src   = (const int*)d_in[4];
    const int* dst   = (const int*)d_in[5];
    float* agg = (float*)d_out;

    // workspace (~42 MB)
    ushort* Xb          = (ushort*)d_ws;                  // 6.4M ushort
    ushort* hMb         = Xb + (size_t)N_NODES * D;       // 6.4M
    ushort* MbT         = hMb + (size_t)N_NODES * D;      // 16384
    ushort* WbT         = MbT + D * D;                    // 16384
    int*    offsets     = (int*)(WbT + D * D);            // 50000
    int*    sorted_dst  = offsets + N_NODES;              // 800000
    int*    bucket_fill = sorted_dst + N_EDGES;           // 256
    int2*   binned      = (int2*)(bucket_fill + 256);     // FB*BCAP int2

    hipMemsetAsync(bucket_fill, 0, 256 * sizeof(int), stream);

    bin_prep_kernel<<<BIN_NBLK + 64, 256, 0, stream>>>(
        src, dst, bucket_fill, binned, W_l, W_r, W, MbT, WbT);

    fine_kernel<<<FB, 256, 0, stream>>>(binned, bucket_fill, offsets, sorted_dst);

    convert_gemm1_kernel<<<GGRID, 256, 0, stream>>>(
        (const float4*)X, Xb, MbT, hMb);

    spmm_gemm2_kernel<<<GGRID, 256, 0, stream>>>(
        hMb, Xb, offsets, sorted_dst, WbT, agg);
}

// Round 10
// 169.642 us; speedup vs baseline: 1.0949x; 1.0949x over previous
//
#include <hip/hip_runtime.h>
#include <hip/hip_bf16.h>

#define N_NODES 50000
#define N_EDGES 800000
#define D 128
#define NEG_SLOPE 0.2f
#define APAD 136                             // LDS row pitch (ushort): 2-way-only bank aliasing

#define FB 196                               // fine buckets: src >> 8 (256 nodes each)
#define BCAP 8192                            // per-bucket region capacity (avg fill ~4096)
#define CHUNK 2048
#define BIN_NBLK ((N_EDGES + CHUNK - 1) / CHUNK)   // 391
#define GROWS 64
#define GGRID ((N_NODES + GROWS - 1) / GROWS)      // 782
#define GEMM_LDS (D * APAD * 2 + GROWS * APAD * 2) // 52224 B

typedef __attribute__((ext_vector_type(8))) short bf16x8;
typedef __attribute__((ext_vector_type(4))) float f32x4;

__device__ inline unsigned short f2bf(float f) {
    union { float f; unsigned u; } v; v.f = f;
    const unsigned r = v.u + 0x7FFF + ((v.u >> 16) & 1);   // round-nearest-even
    return (unsigned short)(r >> 16);
}
__device__ inline unsigned fbits(float f) { union { float f; unsigned u; } v; v.f = f; return v.u; }
__device__ inline float ffrom(unsigned u) { union { unsigned u; float f; } v; v.u = u; return v.f; }

__device__ inline void unpack8(const float4 raw, float* o) {
    const unsigned w0 = fbits(raw.x), w1 = fbits(raw.y), w2 = fbits(raw.z), w3 = fbits(raw.w);
    o[0] = ffrom(w0 << 16); o[1] = ffrom(w0 & 0xffff0000u);
    o[2] = ffrom(w1 << 16); o[3] = ffrom(w1 & 0xffff0000u);
    o[4] = ffrom(w2 << 16); o[5] = ffrom(w2 & 0xffff0000u);
    o[6] = ffrom(w3 << 16); o[7] = ffrom(w3 & 0xffff0000u);
}

__device__ inline int scan256_incl(int* arr, int t, int v) {
    arr[t] = v; __syncthreads();
#pragma unroll
    for (int off = 1; off < 256; off <<= 1) {
        const int u = (t >= off) ? arr[t - off] : 0;
        __syncthreads();
        arr[t] += u;
        __syncthreads();
    }
    return arr[t];
}

// stage a 128x128 bf16 matrix (transposed layout [n][k]) into LDS [n][APAD]
__device__ __forceinline__ void stage_B_lds(unsigned short* Bs, const ushort* __restrict__ BT) {
    const int tid = threadIdx.x;
#pragma unroll
    for (int i = 0; i < 8; ++i) {
        const int idx = tid + i * 256;
        const int row = idx >> 4;
        const int c8 = (idx & 15) << 3;
        const float4 v = ((const float4*)BT)[idx];
        *(float4*)&Bs[row * APAD + c8] = v;
    }
}

// MFMA: C[rb..rb+63][0..127] = As(LDS) @ Bs(LDS, transposed), fp32 acc
template <bool OUT_F32>
__device__ __forceinline__ void mfma_from_lds(const unsigned short* Bs,
                                              const unsigned short* As,
                                              int rb, float* __restrict__ Cf,
                                              ushort* __restrict__ Cb, int nrows) {
    const int tid = threadIdx.x;
    const int w = tid >> 6, lane = tid & 63, m = lane & 15, kq = lane >> 4;
    f32x4 acc[8] = {};
    const unsigned short* Arow = &As[(w * 16 + m) * APAD + kq * 8];
#pragma unroll
    for (int kc = 0; kc < 4; ++kc) {
        const bf16x8 af = *(const bf16x8*)(Arow + kc * 32);
#pragma unroll
        for (int t2 = 0; t2 < 8; ++t2) {
            const bf16x8 bf = *(const bf16x8*)&Bs[(t2 * 16 + m) * APAD + kc * 32 + kq * 8];
            acc[t2] = __builtin_amdgcn_mfma_f32_16x16x32_bf16(af, bf, acc[t2], 0, 0, 0);
        }
    }
    const int orow0 = rb + w * 16 + kq * 4;   // C/D: col=lane&15, row=(lane>>4)*4+reg [m89]
#pragma unroll
    for (int t2 = 0; t2 < 8; ++t2) {
#pragma unroll
        for (int r = 0; r < 4; ++r) {
            const int row = orow0 + r;
            if (row < nrows) {
                const size_t o = (size_t)row * D + t2 * 16 + m;
                if (OUT_F32) Cf[o] = acc[t2][r];
                else         Cb[o] = f2bf(acc[t2][r]);
            }
        }
    }
}

// ---- K0 (tiny): weight prep + zero bucket_fill. MUST be its own dispatch:
// consumers (K1 gemm1 branch / K4) are separate launches -> stream-ordered.
// (R9 bug: fusing this into K1 created an unordered cross-block dependency.)
__global__ __launch_bounds__(256) void prep_kernel(const float* __restrict__ W_l,
                                                   const float* __restrict__ W_r,
                                                   const float* __restrict__ W,
                                                   ushort* __restrict__ MbT,
                                                   ushort* __restrict__ WbT,
                                                   int* __restrict__ bucket_fill) {
    if (blockIdx.x == 0) bucket_fill[threadIdx.x] = 0;   // 256 entries
    // MbT[n][k] = (W_l @ W_r^T)[k][n]; WbT[n][k] = W[k][n]
    const int a = blockIdx.x * 2 + (threadIdx.x >> 7);   // k
    const int b2 = threadIdx.x & 127;                    // n
    float acc = 0.f;
#pragma unroll
    for (int c = 0; c < D; c += 4) {
        const float4 wl = *(const float4*)(W_l + a * D + c);
        const float4 wr = *(const float4*)(W_r + b2 * D + c);
        acc += wl.x * wr.x + wl.y * wr.y + wl.z * wr.z + wl.w * wr.w;
    }
    MbT[b2 * D + a] = f2bf(acc);
    WbT[b2 * D + a] = f2bf(W[a * D + b2]);
}

// ---- K1: bin (blocks 0..390) + convert_gemm1 (391..) — independent work merged ----
__global__ __launch_bounds__(256) void k1_kernel(const int* __restrict__ src,
                                                 const int* __restrict__ dst,
                                                 int* __restrict__ bucket_fill,
                                                 int2* __restrict__ binned,
                                                 const ushort* __restrict__ MbT,
                                                 const float4* __restrict__ Xf4,
                                                 ushort* __restrict__ Xb,
                                                 ushort* __restrict__ hMb) {
    __shared__ __align__(16) char smem[GEMM_LDS];
    const int bx = blockIdx.x;
    const int t = threadIdx.x;

    if (bx < BIN_NBLK) {
        // ---- binning: CHUNK edges staged+compacted in LDS, run-written per bucket ----
        int*  hist     = (int*)smem;                 // 256
        int*  bstart   = hist + 256;                 // 256
        int*  reserveS = bstart + 256;               // 256
        int*  fillL    = reserveS + 256;             // 256
        int2* pairs    = (int2*)(fillL + 256);       // CHUNK (16 KB)
        int*  targ     = (int*)(pairs + CHUNK);      // CHUNK (8 KB)
        const int e0 = bx * CHUNK;

        hist[t] = 0;
        __syncthreads();

        int s[8], d[8], b[8];
#pragma unroll
        for (int i = 0; i < 8; ++i) {
            const int e = e0 + i * 256 + t;
            if (e < N_EDGES) {
                s[i] = src[e]; d[i] = dst[e]; b[i] = s[i] >> 8;
                atomicAdd(&hist[b[i]], 1);
            } else b[i] = -1;
        }
        __syncthreads();
        const int hv = hist[t];
        const int incl = scan256_incl(bstart, t, hv);
        const int mystart = incl - hv;
        reserveS[t] = hv ? atomicAdd(&bucket_fill[t], hv) : 0;
        __syncthreads();
        bstart[t] = mystart;
        fillL[t] = mystart;
        __syncthreads();
#pragma unroll
        for (int i = 0; i < 8; ++i) {
            if (b[i] >= 0) {
                const int p = atomicAdd(&fillL[b[i]], 1);
                pairs[p] = make_int2(s[i], d[i]);
                const int pos = reserveS[b[i]] + (p - bstart[b[i]]);
                targ[p] = (pos < BCAP) ? (b[i] * BCAP + pos) : -1;   // overflow guard
            }
        }
        __syncthreads();
        const int nval = min(CHUNK, N_EDGES - e0);
        for (int j = t; j < nval; j += 256)
            if (targ[j] >= 0) binned[targ[j]] = pairs[j];
    } else {
        // ---- convert 64 X-rows fp32->bf16 (global + LDS) then hM = Xb@M ----
        unsigned short* Bs = (unsigned short*)smem;     // [128][APAD]
        unsigned short* As = Bs + D * APAD;             // [64][APAD]
        const int rb = (bx - BIN_NBLK) * GROWS;

        stage_B_lds(Bs, MbT);                           // MbT from K0 (stream-ordered)
#pragma unroll
        for (int i = 0; i < 4; ++i) {
            const int f2 = t + i * 256;
            const int row = f2 >> 4;
            const int c8 = (f2 & 15) << 3;
            ushort4 lo = {0, 0, 0, 0}, hi = {0, 0, 0, 0};
            if (rb + row < N_NODES) {
                const float4 a = Xf4[(size_t)(rb + row) * 32 + (c8 >> 2)];
                const float4 b = Xf4[(size_t)(rb + row) * 32 + (c8 >> 2) + 1];
                lo.x = f2bf(a.x); lo.y = f2bf(a.y); lo.z = f2bf(a.z); lo.w = f2bf(a.w);
                hi.x = f2bf(b.x); hi.y = f2bf(b.y); hi.z = f2bf(b.z); hi.w = f2bf(b.w);
                ushort* gp = Xb + (size_t)(rb + row) * D + c8;
                *(ushort4*)gp = lo;
                *(ushort4*)(gp + 4) = hi;
            }
            *(ushort4*)&As[row * APAD + c8] = lo;
            *(ushort4*)&As[row * APAD + c8 + 4] = hi;
        }
        __syncthreads();
        mfma_from_lds<false>(Bs, As, rb, nullptr, hMb, N_NODES);
    }
}

// ---- K2: fine scatter, one 512-thread block per bucket; builds offsets+sorted_dst ----
__global__ __launch_bounds__(512) void fine_kernel(const int2* __restrict__ binned,
                                                   const int* __restrict__ bucket_fill,
                                                   int* __restrict__ offsets,
                                                   int* __restrict__ sorted_dst) {
    __shared__ int cntS[256];
    __shared__ int nh[256];
    __shared__ int ex[256];
    __shared__ int fill[256];
    __shared__ int dstbuf[BCAP];
    const int b = blockIdx.x;
    const int t = threadIdx.x;

    if (t < 256) cntS[t] = (t < FB) ? bucket_fill[t] : 0;
    __syncthreads();
#pragma unroll
    for (int off = 1; off < 256; off <<= 1) {     // guarded Hillis-Steele (256 entries)
        const int u = (t >= off && t < 256) ? cntS[t - off] : 0;
        __syncthreads();
        if (t < 256) cntS[t] += u;
        __syncthreads();
    }
    const int base = (b == 0) ? 0 : cntS[b - 1];
    int cnt = cntS[b] - base;
    if (cnt > BCAP) cnt = BCAP;

    if (t < 256) nh[t] = 0;
    __syncthreads();
    const int2* bb = binned + (size_t)b * BCAP;
    for (int e = t; e < cnt; e += 512) atomicAdd(&nh[bb[e].x & 255], 1);
    __syncthreads();
    const int v = (t < 256) ? nh[t] : 0;
    if (t < 256) ex[t] = v;
    __syncthreads();
#pragma unroll
    for (int off = 1; off < 256; off <<= 1) {
        const int u = (t >= off && t < 256) ? ex[t - off] : 0;
        __syncthreads();
        if (t < 256) ex[t] += u;
        __syncthreads();
    }
    if (t < 256) {
        const int mystart = ex[t] - v;
        const int node = b * 256 + t;
        if (node < N_NODES) offsets[node] = base + mystart;   // exclusive CSR starts
        fill[t] = mystart;
    }
    __syncthreads();
    for (int e = t; e < cnt; e += 512) {
        const int2 sd = bb[e];
        const int p = atomicAdd(&fill[sd.x & 255], 1);
        dstbuf[p] = sd.y;
    }
    __syncthreads();
    for (int j = t; j < cnt; j += 512)
        sorted_dst[base + j] = dstbuf[j];
}

// ---- K3: fused SDDMM + SpMM, quarter-wave per edge, unroll 4 (R7-proven) ----
__global__ __launch_bounds__(256) void spmm_kernel(const ushort* __restrict__ hMb,
                                                   const ushort* __restrict__ Xb,
                                                   const int* __restrict__ offsets,
                                                   const int* __restrict__ sorted_dst,
                                                   ushort* __restrict__ aggXb) {
    const int wave = threadIdx.x >> 6;
    const int lane = threadIdx.x & 63;
    const int node = blockIdx.x * 4 + wave;      // 12500*4 = 50000 exact
    const int q = lane >> 4;
    const int ql = lane & 15;

    float hm[8];
    unpack8(*(const float4*)(hMb + (size_t)node * D + ql * 8), hm);

    const int start = offsets[node];
    const int end = (node == N_NODES - 1) ? N_EDGES : offsets[node + 1];

    float acc[8] = {0.f, 0.f, 0.f, 0.f, 0.f, 0.f, 0.f, 0.f};

    int idx = start + q;
    while (idx + 12 < end) {
        const int d0 = sorted_dst[idx];
        const int d1 = sorted_dst[idx + 4];
        const int d2 = sorted_dst[idx + 8];
        const int d3 = sorted_dst[idx + 12];
        const float4 r0 = *(const float4*)(Xb + (size_t)d0 * D + ql * 8);
        const float4 r1 = *(const float4*)(Xb + (size_t)d1 * D + ql * 8);
        const float4 r2 = *(const float4*)(Xb + (size_t)d2 * D + ql * 8);
        const float4 r3 = *(const float4*)(Xb + (size_t)d3 * D + ql * 8);
        float t0 = 0.f, t1 = 0.f, t2 = 0.f, t3 = 0.f;
        {
            float x[8];
            unpack8(r0, x);
#pragma unroll
            for (int j = 0; j < 8; ++j) t0 = fmaf(hm[j], x[j], t0);
            unpack8(r1, x);
#pragma unroll
            for (int j = 0; j < 8; ++j) t1 = fmaf(hm[j], x[j], t1);
            unpack8(r2, x);
#pragma unroll
            for (int j = 0; j < 8; ++j) t2 = fmaf(hm[j], x[j], t2);
            unpack8(r3, x);
#pragma unroll
            for (int j = 0; j < 8; ++j) t3 = fmaf(hm[j], x[j], t3);
        }
#pragma unroll
        for (int mm = 1; mm < 16; mm <<= 1) {
            t0 += __shfl_xor(t0, mm);
            t1 += __shfl_xor(t1, mm);
            t2 += __shfl_xor(t2, mm);
            t3 += __shfl_xor(t3, mm);
        }
        const float e0 = t0 > 0.f ? t0 : NEG_SLOPE * t0;
        const float e1 = t1 > 0.f ? t1 : NEG_SLOPE * t1;
        const float e2 = t2 > 0.f ? t2 : NEG_SLOPE * t2;
        const float e3 = t3 > 0.f ? t3 : NEG_SLOPE * t3;
        {
            float x[8];
            unpack8(r0, x);
#pragma unroll
            for (int j = 0; j < 8; ++j) acc[j] = fmaf(e0, x[j], acc[j]);
            unpack8(r1, x);
#pragma unroll
            for (int j = 0; j < 8; ++j) acc[j] = fmaf(e1, x[j], acc[j]);
            unpack8(r2, x);
#pragma unroll
            for (int j = 0; j < 8; ++j) acc[j] = fmaf(e2, x[j], acc[j]);
            unpack8(r3, x);
#pragma unroll
            for (int j = 0; j < 8; ++j) acc[j] = fmaf(e3, x[j], acc[j]);
        }
        idx += 16;
    }
    while (idx < end) {
        const int d0 = sorted_dst[idx];
        const float4 r0 = *(const float4*)(Xb + (size_t)d0 * D + ql * 8);
        float x[8];
        unpack8(r0, x);
        float t0 = 0.f;
#pragma unroll
        for (int j = 0; j < 8; ++j) t0 = fmaf(hm[j], x[j], t0);
#pragma unroll
        for (int mm = 1; mm < 16; mm <<= 1) t0 += __shfl_xor(t0, mm);
        const float e0 = t0 > 0.f ? t0 : NEG_SLOPE * t0;
#pragma unroll
        for (int j = 0; j < 8; ++j) acc[j] = fmaf(e0, x[j], acc[j]);
        idx += 4;
    }

#pragma unroll
    for (int j = 0; j < 8; ++j) {
        acc[j] += __shfl_xor(acc[j], 16);
        acc[j] += __shfl_xor(acc[j], 32);
    }
    if (q == 0) {
        ushort4 o0, o1;
        o0.x = f2bf(acc[0]); o0.y = f2bf(acc[1]); o0.z = f2bf(acc[2]); o0.w = f2bf(acc[3]);
        o1.x = f2bf(acc[4]); o1.y = f2bf(acc[5]); o1.z = f2bf(acc[6]); o1.w = f2bf(acc[7]);
        ushort* outp = aggXb + (size_t)node * D + ql * 8;
        *(ushort4*)outp = o0;
        *(ushort4*)(outp + 4) = o1;
    }
}

// ---- K4: agg = aggX @ W ----
__global__ __launch_bounds__(256) void gemm2_kernel(const ushort* __restrict__ A,
                                                    const ushort* __restrict__ BT,
                                                    float* __restrict__ Cf) {
    __shared__ __align__(16) char smem[GEMM_LDS];
    unsigned short* Bs = (unsigned short*)smem;
    unsigned short* As = Bs + D * APAD;
    const int tid = threadIdx.x;
    const int rb = blockIdx.x * GROWS;

    stage_B_lds(Bs, BT);
#pragma unroll
    for (int i = 0; i < 4; ++i) {
        const int idx = tid + i * 256;
        const int row = idx >> 4;
        const int c8 = (idx & 15) << 3;
        float4 v = {0.f, 0.f, 0.f, 0.f};
        if (rb + row < N_NODES)
            v = ((const float4*)(A + (size_t)(rb + row) * D))[idx & 15];
        *(float4*)&As[row * APAD + c8] = v;
    }
    __syncthreads();
    mfma_from_lds<true>(Bs, As, rb, Cf, nullptr, N_NODES);
}

extern "C" void kernel_launch(void* const* d_in, const int* in_sizes, int n_in,
                              void* d_out, int out_size, void* d_ws, size_t ws_size,
                              hipStream_t stream) {
    const float* X   = (const float*)d_in[0];
    const float* W   = (const float*)d_in[1];
    const float* W_r = (const float*)d_in[2];
    const float* W_l = (const float*)d_in[3];
    const int* src   = (const int*)d_in[4];
    const int* dst   = (const int*)d_in[5];
    float* agg = (float*)d_out;

    // workspace (~48 MB)
    ushort* Xb          = (ushort*)d_ws;                  // 6.4M ushort
    ushort* hMb         = Xb + (size_t)N_NODES * D;       // 6.4M
    ushort* aggXb       = hMb + (size_t)N_NODES * D;      // 6.4M
    ushort* MbT         = aggXb + (size_t)N_NODES * D;    // 16384
    ushort* WbT         = MbT + D * D;                    // 16384
    int*    offsets     = (int*)(WbT + D * D);            // 50000
    int*    sorted_dst  = offsets + N_NODES;              // 800000
    int*    bucket_fill = sorted_dst + N_EDGES;           // 256
    int2*   binned      = (int2*)(bucket_fill + 256);     // FB*BCAP int2

    prep_kernel<<<64, 256, 0, stream>>>(W_l, W_r, W, MbT, WbT, bucket_fill);

    k1_kernel<<<BIN_NBLK + GGRID, 256, 0, stream>>>(
        src, dst, bucket_fill, binned, MbT, (const float4*)X, Xb, hMb);

    fine_kernel<<<FB, 512, 0, stream>>>(binned, bucket_fill, offsets, sorted_dst);

    spmm_kernel<<<N_NODES / 4, 256, 0, stream>>>(hMb, Xb, offsets, sorted_dst, aggXb);

    gemm2_kernel<<<GGRID, 256, 0, stream>>>(aggXb, WbT, agg);
}